// Round 1
// baseline (469.691 us; speedup 1.0000x reference)
//
#include <hip/hip_runtime.h>
#include <math.h>

#define NN 100000
#define NE 1200000
#define D  64
#define BN_EPS 1e-5f

// ---------------------------------------------------------------------------
// Kernel 1: edge scatter. 64 lanes per edge (one wave == one edge).
// Lane d: agg[dst*64+d] += x[src*64+d]; lane 0 also counts the edge.
// Reads are 256B-coalesced per wave; atomics are 256B-contiguous per wave.
// ---------------------------------------------------------------------------
__global__ __launch_bounds__(256) void scatter_kernel(
        const float* __restrict__ x,
        const int*   __restrict__ ei,   // [2, NE] row-major: src at [e], dst at [NE+e]
        float* __restrict__ agg,
        float* __restrict__ cnt) {
    int gid = blockIdx.x * blockDim.x + threadIdx.x;   // < 76.8M, fits int
    if (gid >= NE * D) return;
    int e = gid >> 6;
    int d = gid & 63;
    int src = ei[e];
    int dst = ei[NE + e];
    atomicAdd(&agg[(size_t)dst * D + d], x[(size_t)src * D + d]);
    if (d == 0) atomicAdd(&cnt[dst], 1.0f);
}

// ---------------------------------------------------------------------------
// Kernel 2: fused mean-divide + (mean @ W) + ELU + BN-stat partial reduce.
// Block = 256 threads = 4 rows x 64 cols. W staged in LDS (16 KB).
// h overwrites agg in place (row fully consumed before written).
// ---------------------------------------------------------------------------
__global__ __launch_bounds__(256) void gemm_elu_stats_kernel(
        float* __restrict__ buf,        // in: agg, out: h
        const float* __restrict__ cnt,
        const float* __restrict__ W,    // [D_IN, D_OUT] row-major
        float* __restrict__ stats) {    // [0..63]=sum, [64..127]=sumsq
    __shared__ float Ws[D * D];
    __shared__ float rows[4][D];
    __shared__ float red[2][256];

    for (int i = threadIdx.x; i < D * D; i += 256) Ws[i] = W[i];

    const int rl = threadIdx.x >> 6;   // row slot 0..3
    const int c  = threadIdx.x & 63;   // output column

    float s = 0.f, s2 = 0.f;
    const int nIter = (NN + 3) / 4;    // 25000
    for (int it = blockIdx.x; it < nIter; it += gridDim.x) {
        const int r = it * 4 + rl;
        __syncthreads();               // previous iteration done with rows[]
        if (r < NN) rows[rl][c] = buf[(size_t)r * D + c];
        __syncthreads();
        if (r < NN) {
            const float inv = 1.0f / fmaxf(cnt[r], 1.0f);
            float acc = 0.f;
            #pragma unroll
            for (int k = 0; k < D; ++k)
                acc = fmaf(rows[rl][k], Ws[k * D + c], acc);
            acc *= inv;                             // (agg*inv)@W == inv*(agg@W)
            const float h = acc > 0.f ? acc : expm1f(acc);
            buf[(size_t)r * D + c] = h;
            s  += h;
            s2 += h * h;
        }
    }

    red[0][threadIdx.x] = s;
    red[1][threadIdx.x] = s2;
    __syncthreads();
    if (threadIdx.x < 64) {
        float ts  = red[0][threadIdx.x] + red[0][threadIdx.x + 64] +
                    red[0][threadIdx.x + 128] + red[0][threadIdx.x + 192];
        float ts2 = red[1][threadIdx.x] + red[1][threadIdx.x + 64] +
                    red[1][threadIdx.x + 128] + red[1][threadIdx.x + 192];
        atomicAdd(&stats[threadIdx.x],      ts);
        atomicAdd(&stats[64 + threadIdx.x], ts2);
    }
}

// ---------------------------------------------------------------------------
// Kernel 3: BatchNorm finalize. Pure streaming.
// ---------------------------------------------------------------------------
__global__ __launch_bounds__(256) void bn_kernel(
        const float* __restrict__ h,
        const float* __restrict__ stats,
        const float* __restrict__ gamma,
        const float* __restrict__ beta,
        float* __restrict__ out) {
    int gid = blockIdx.x * blockDim.x + threadIdx.x;
    if (gid >= NN * D) return;
    const int c = gid & 63;
    const float mu  = stats[c] * (1.0f / NN);
    const float var = stats[64 + c] * (1.0f / NN) - mu * mu;
    const float is  = rsqrtf(var + BN_EPS);
    out[gid] = (h[gid] - mu) * is * gamma[c] + beta[c];
}

extern "C" void kernel_launch(void* const* d_in, const int* in_sizes, int n_in,
                              void* d_out, int out_size, void* d_ws, size_t ws_size,
                              hipStream_t stream) {
    const float* x     = (const float*)d_in[0];
    const int*   ei    = (const int*)  d_in[1];
    const float* W     = (const float*)d_in[2];
    const float* gamma = (const float*)d_in[3];
    const float* beta  = (const float*)d_in[4];
    float* out = (float*)d_out;

    // workspace layout: agg/h [NN*D] | cnt [NN] | stats [128]
    float* agg   = (float*)d_ws;
    float* cnt   = agg + (size_t)NN * D;
    float* stats = cnt + NN;

    const size_t zero_bytes = ((size_t)NN * D + NN + 128) * sizeof(float);
    hipMemsetAsync(d_ws, 0, zero_bytes, stream);

    const int total1 = NE * D;
    scatter_kernel<<<(total1 + 255) / 256, 256, 0, stream>>>(x, ei, agg, cnt);
    gemm_elu_stats_kernel<<<1024, 256, 0, stream>>>(agg, cnt, W, stats);
    bn_kernel<<<(NN * D + 255) / 256, 256, 0, stream>>>(agg, stats, gamma, beta, out);
}

// Round 2
// 389.595 us; speedup vs baseline: 1.2056x; 1.2056x over previous
//
#include <hip/hip_runtime.h>
#include <math.h>

#define NN 100000
#define NE 1200000
#define D  64
#define BN_EPS 1e-5f
#define SCAN_B 1024
#define NBLK ((NN + SCAN_B - 1) / SCAN_B)   // 98

// ---------------------------------------------------------------------------
// CSR build step 1: histogram of dst. 1.2M int atomics (64x fewer than the
// old fp32 scatter).
// ---------------------------------------------------------------------------
__global__ __launch_bounds__(256) void hist_kernel(
        const int* __restrict__ ei, int* __restrict__ count) {
    int e = blockIdx.x * 256 + threadIdx.x;
    if (e < NE) atomicAdd(&count[ei[NE + e]], 1);
}

// ---------------------------------------------------------------------------
// CSR build step 2a: per-block exclusive scan (1024 elems/block, 98 blocks).
// ---------------------------------------------------------------------------
__global__ __launch_bounds__(SCAN_B) void scan1_kernel(
        const int* __restrict__ count, int* __restrict__ exc,
        int* __restrict__ bsum) {
    __shared__ int tmp[SCAN_B];
    const int tid = threadIdx.x;
    const int i = blockIdx.x * SCAN_B + tid;
    const int v = (i < NN) ? count[i] : 0;
    tmp[tid] = v;
    __syncthreads();
    for (int off = 1; off < SCAN_B; off <<= 1) {   // Hillis-Steele inclusive
        int t = (tid >= off) ? tmp[tid - off] : 0;
        __syncthreads();
        tmp[tid] += t;
        __syncthreads();
    }
    if (i < NN) exc[i] = tmp[tid] - v;              // exclusive
    if (tid == SCAN_B - 1) bsum[blockIdx.x] = tmp[tid];
}

// ---------------------------------------------------------------------------
// CSR build step 2b: scan the 98 block sums (single block).
// ---------------------------------------------------------------------------
__global__ __launch_bounds__(128) void scan2_kernel(
        const int* __restrict__ bsum, int* __restrict__ boff) {
    __shared__ int tmp[128];
    const int tid = threadIdx.x;
    const int v = (tid < NBLK) ? bsum[tid] : 0;
    tmp[tid] = v;
    __syncthreads();
    for (int off = 1; off < 128; off <<= 1) {
        int t = (tid >= off) ? tmp[tid - off] : 0;
        __syncthreads();
        tmp[tid] += t;
        __syncthreads();
    }
    boff[tid] = tmp[tid] - v;                       // exclusive
}

// ---------------------------------------------------------------------------
// CSR build step 2c: combine scans -> start[]; init cursor[].
// ---------------------------------------------------------------------------
__global__ __launch_bounds__(256) void scan3_kernel(
        const int* __restrict__ exc, const int* __restrict__ boff,
        int* __restrict__ start, int* __restrict__ cursor) {
    int i = blockIdx.x * 256 + threadIdx.x;
    if (i < NN) {
        int s = exc[i] + boff[i >> 10];
        start[i] = s;
        cursor[i] = s;
    }
    if (i == 0) start[NN] = NE;
}

// ---------------------------------------------------------------------------
// CSR build step 3: bucket the src indices by dst. 1.2M int atomics.
// ---------------------------------------------------------------------------
__global__ __launch_bounds__(256) void reorder_kernel(
        const int* __restrict__ ei, int* __restrict__ cursor,
        int* __restrict__ srcSorted) {
    int e = blockIdx.x * 256 + threadIdx.x;
    if (e < NE) {
        int dst = ei[NE + e];
        int pos = atomicAdd(&cursor[dst], 1);
        srcSorted[pos] = ei[e];
    }
}

// ---------------------------------------------------------------------------
// Fused: gather-aggregate (one wave per node, lane = feature) -> mean ->
// @W -> ELU -> h write + BN-stat partials. Persistent blocks: W staged in
// LDS once. No fp32 atomics except 128/block stat adds at the end.
// LDS: 16KB (Ws) + 1KB (mean) + 2KB (red) -> 8 blocks/CU.
// ---------------------------------------------------------------------------
__global__ __launch_bounds__(256) void agg_gemm_kernel(
        const float* __restrict__ x,
        const int*   __restrict__ start,
        const int*   __restrict__ srcSorted,
        const float* __restrict__ W,       // [D_IN, D_OUT] row-major
        float* __restrict__ h,
        float* __restrict__ stats) {       // [0..63]=sum, [64..127]=sumsq
    __shared__ float Ws[D * D];
    __shared__ float mean[4][D];
    __shared__ float red[2][256];

    for (int i = threadIdx.x; i < D * D; i += 256) Ws[i] = W[i];

    const int w    = threadIdx.x >> 6;    // wave slot 0..3 == row slot
    const int lane = threadIdx.x & 63;    // feature / output column

    float s = 0.f, s2 = 0.f;
    const int nGroups = (NN + 3) / 4;     // 25000
    for (int g = blockIdx.x; g < nGroups; g += gridDim.x) {
        const int node = g * 4 + w;
        __syncthreads();                  // mean[] free from previous iter
        if (node < NN) {
            const int e0 = start[node], e1 = start[node + 1];
            float acc = 0.f;
            for (int j = e0; j < e1; ++j) {
                const int src = srcSorted[j];        // broadcast read
                acc += x[(size_t)src * D + lane];    // 256B/wave coalesced
            }
            mean[w][lane] = acc * (1.0f / fmaxf((float)(e1 - e0), 1.0f));
        } else {
            mean[w][lane] = 0.f;
        }
        __syncthreads();
        if (node < NN) {
            float acc = 0.f;
            #pragma unroll
            for (int k = 0; k < D; ++k)              // mean[w][k] broadcasts
                acc = fmaf(mean[w][k], Ws[k * D + lane], acc);
            const float hv = acc > 0.f ? acc : expm1f(acc);
            h[(size_t)node * D + lane] = hv;
            s  += hv;
            s2 += hv * hv;
        }
    }

    red[0][threadIdx.x] = s;
    red[1][threadIdx.x] = s2;
    __syncthreads();
    if (threadIdx.x < 64) {
        float ts  = red[0][threadIdx.x] + red[0][threadIdx.x + 64] +
                    red[0][threadIdx.x + 128] + red[0][threadIdx.x + 192];
        float ts2 = red[1][threadIdx.x] + red[1][threadIdx.x + 64] +
                    red[1][threadIdx.x + 128] + red[1][threadIdx.x + 192];
        atomicAdd(&stats[threadIdx.x],      ts);
        atomicAdd(&stats[64 + threadIdx.x], ts2);
    }
}

// ---------------------------------------------------------------------------
// BatchNorm finalize, float4-vectorized streaming.
// ---------------------------------------------------------------------------
__global__ __launch_bounds__(256) void bn_kernel(
        const float4* __restrict__ h,
        const float*  __restrict__ stats,
        const float*  __restrict__ gamma,
        const float*  __restrict__ beta,
        float4* __restrict__ out) {
    int gid = blockIdx.x * 256 + threadIdx.x;     // over NN*D/4
    if (gid >= NN * D / 4) return;
    const int c0 = (gid & 15) * 4;
    const float4 v = h[gid];
    float4 r;
    const float* vv = (const float*)&v;
    float* rr = (float*)&r;
    #pragma unroll
    for (int k = 0; k < 4; ++k) {
        const int c = c0 + k;
        const float mu  = stats[c] * (1.0f / NN);
        const float var = stats[64 + c] * (1.0f / NN) - mu * mu;
        const float is  = rsqrtf(var + BN_EPS);
        rr[k] = (vv[k] - mu) * is * gamma[c] + beta[c];
    }
    out[gid] = r;
}

extern "C" void kernel_launch(void* const* d_in, const int* in_sizes, int n_in,
                              void* d_out, int out_size, void* d_ws, size_t ws_size,
                              hipStream_t stream) {
    const float* x     = (const float*)d_in[0];
    const int*   ei    = (const int*)  d_in[1];
    const float* W     = (const float*)d_in[2];
    const float* gamma = (const float*)d_in[3];
    const float* beta  = (const float*)d_in[4];
    float* out = (float*)d_out;

    // workspace layout (floats/ints, 4B units):
    // [buf NN*D][count NN][stats 128][exc NN][start NN+1][cursor NN]
    // [bsum 128][boff 128][srcSorted NE]   total ~31.3 MB
    float* buf       = (float*)d_ws;
    int*   count     = (int*)(buf + (size_t)NN * D);
    float* stats     = (float*)(count + NN);
    int*   exc       = (int*)(stats + 128);
    int*   start     = exc + NN;
    int*   cursor    = start + NN + 1;
    int*   bsum      = cursor + NN;
    int*   boff      = bsum + 128;
    int*   srcSorted = boff + 128;

    // zero count + stats (contiguous)
    hipMemsetAsync(count, 0, (size_t)(NN + 128) * sizeof(int), stream);

    hist_kernel   <<<(NE + 255) / 256, 256, 0, stream>>>(ei, count);
    scan1_kernel  <<<NBLK, SCAN_B, 0, stream>>>(count, exc, bsum);
    scan2_kernel  <<<1, 128, 0, stream>>>(bsum, boff);
    scan3_kernel  <<<(NN + 255) / 256, 256, 0, stream>>>(exc, boff, start, cursor);
    reorder_kernel<<<(NE + 255) / 256, 256, 0, stream>>>(ei, cursor, srcSorted);
    agg_gemm_kernel<<<2048, 256, 0, stream>>>(x, start, srcSorted, W, buf, stats);
    bn_kernel     <<<(NN * D / 4 + 255) / 256, 256, 0, stream>>>(
        (const float4*)buf, stats, gamma, beta, (float4*)out);
}

// Round 3
// 316.766 us; speedup vs baseline: 1.4828x; 1.2299x over previous
//
#include <hip/hip_runtime.h>
#include <math.h>

#define NN  100000
#define NNP 100352            // NN padded to a multiple of 1024
#define NE  1200000
#define D   64
#define BN_EPS 1e-5f
#define NBLK (NNP / 1024)     // 98 scan blocks

__device__ __forceinline__ float bcastf(float v, int srcLane) {
    return __int_as_float(__builtin_amdgcn_readlane(__float_as_int(v), srcLane));
}

// ---------------------------------------------------------------------------
// CSR build step 1: histogram of dst.
// ---------------------------------------------------------------------------
__global__ __launch_bounds__(256) void hist_kernel(
        const int* __restrict__ ei, int* __restrict__ count) {
    int e = blockIdx.x * 256 + threadIdx.x;
    if (e < NE) atomicAdd(&count[ei[NE + e]], 1);
}

// ---------------------------------------------------------------------------
// CSR build step 2a: per-block exclusive scan, 1024 ints/block via int4 +
// wave shfl scan (2 barriers instead of 20).
// ---------------------------------------------------------------------------
__global__ __launch_bounds__(256) void scan1_kernel(
        const int4* __restrict__ countv, int4* __restrict__ excv,
        int* __restrict__ bsum) {
    __shared__ int wsum[4];
    __shared__ int wexc[4];
    const int tid  = threadIdx.x;
    const int lane = tid & 63;
    const int wid  = tid >> 6;
    const int idx  = blockIdx.x * 256 + tid;

    int4 v = countv[idx];                    // padded region is zeroed
    const int s = v.x + v.y + v.z + v.w;
    int incl = s;
    #pragma unroll
    for (int off = 1; off < 64; off <<= 1) {
        int n = __shfl_up(incl, off, 64);
        if (lane >= off) incl += n;
    }
    if (lane == 63) wsum[wid] = incl;
    __syncthreads();
    if (tid == 0) {
        int r = 0;
        #pragma unroll
        for (int w = 0; w < 4; ++w) { wexc[w] = r; r += wsum[w]; }
        bsum[blockIdx.x] = r;
    }
    __syncthreads();
    const int base = wexc[wid] + (incl - s);
    int4 e;
    e.x = base;
    e.y = e.x + v.x;
    e.z = e.y + v.y;
    e.w = e.z + v.z;
    excv[idx] = e;
}

// ---------------------------------------------------------------------------
// CSR build step 2b: scan the 98 block sums (single tiny block).
// ---------------------------------------------------------------------------
__global__ __launch_bounds__(128) void scan2_kernel(
        const int* __restrict__ bsum, int* __restrict__ boff) {
    __shared__ int tmp[128];
    const int tid = threadIdx.x;
    const int v = (tid < NBLK) ? bsum[tid] : 0;
    tmp[tid] = v;
    __syncthreads();
    for (int off = 1; off < 128; off <<= 1) {
        int t = (tid >= off) ? tmp[tid - off] : 0;
        __syncthreads();
        tmp[tid] += t;
        __syncthreads();
    }
    boff[tid] = tmp[tid] - v;                       // exclusive
}

// ---------------------------------------------------------------------------
// CSR build step 2c: combine scans -> start[]; init cursor[].
// ---------------------------------------------------------------------------
__global__ __launch_bounds__(256) void scan3_kernel(
        const int* __restrict__ exc, const int* __restrict__ boff,
        int* __restrict__ start, int* __restrict__ cursor) {
    int i = blockIdx.x * 256 + threadIdx.x;
    if (i < NN) {
        int s = exc[i] + boff[i >> 10];
        start[i] = s;
        cursor[i] = s;
    }
    if (i == 0) start[NN] = NE;
}

// ---------------------------------------------------------------------------
// CSR build step 3: bucket src indices by dst.
// ---------------------------------------------------------------------------
__global__ __launch_bounds__(256) void reorder_kernel(
        const int* __restrict__ ei, int* __restrict__ cursor,
        int* __restrict__ srcSorted) {
    int e = blockIdx.x * 256 + threadIdx.x;
    if (e < NE) {
        int dst = ei[NE + e];
        int pos = atomicAdd(&cursor[dst], 1);
        srcSorted[pos] = ei[e];
    }
}

// ---------------------------------------------------------------------------
// Fused gather-aggregate -> mean -> @W -> ELU -> h + BN-stat partials.
// One wave per node. Gather: 4 edges/instr (lane = (group, float4-slot)),
// unrolled x2 (8 edges in flight). Mean broadcast via v_readlane (VALU);
// W transposed/packed in LDS, read as contiguous b128 (conflict-free).
// No __syncthreads in the main loop.
// ---------------------------------------------------------------------------
__global__ __launch_bounds__(256) void agg_gemm_kernel(
        const float4* __restrict__ xv,          // x as [NN][16] float4
        const int*    __restrict__ start,
        const int*    __restrict__ srcSorted,
        const float*  __restrict__ W,           // [D_IN, D_OUT] row-major
        float* __restrict__ h,
        float* __restrict__ stats) {            // [0..63]=sum, [64..127]=sumsq
    __shared__ float4 Wt2[16 * 64];             // [k0][c] = W[4k0..4k0+3][c]
    __shared__ float red[2][256];

    for (int i = threadIdx.x; i < D * D; i += 256) {
        const float val = W[i];
        const int k = i >> 6, c = i & 63;
        ((float*)&Wt2[(k >> 2) * 64 + c])[k & 3] = val;
    }
    __syncthreads();

    const int w    = threadIdx.x >> 6;          // wave slot == node slot
    const int lane = threadIdx.x & 63;
    const int g    = lane >> 4;                 // edge group 0..3
    const int t    = lane & 15;                 // float4 slot within row

    float s = 0.f, s2 = 0.f;
    const int nGroups = (NN + 3) / 4;           // 25000
    for (int grp = blockIdx.x; grp < nGroups; grp += gridDim.x) {
        const int node = grp * 4 + w;
        if (node < NN) {
            const int e0 = start[node], e1 = start[node + 1];
            float4 acc = make_float4(0.f, 0.f, 0.f, 0.f);
            int j = e0 + g;
            for (; j + 4 < e1; j += 8) {        // 8 edges in flight per wave
                const int s0 = srcSorted[j];
                const int s1 = srcSorted[j + 4];
                const float4 v0 = xv[(size_t)s0 * 16 + t];
                const float4 v1 = xv[(size_t)s1 * 16 + t];
                acc.x += v0.x + v1.x;
                acc.y += v0.y + v1.y;
                acc.z += v0.z + v1.z;
                acc.w += v0.w + v1.w;
            }
            if (j < e1) {
                const int s0 = srcSorted[j];
                const float4 v0 = xv[(size_t)s0 * 16 + t];
                acc.x += v0.x; acc.y += v0.y; acc.z += v0.z; acc.w += v0.w;
            }
            // sum the 4 edge-groups: butterfly across lanes (xor 16, 32)
            acc.x += __shfl_xor(acc.x, 16, 64);
            acc.y += __shfl_xor(acc.y, 16, 64);
            acc.z += __shfl_xor(acc.z, 16, 64);
            acc.w += __shfl_xor(acc.w, 16, 64);
            acc.x += __shfl_xor(acc.x, 32, 64);
            acc.y += __shfl_xor(acc.y, 32, 64);
            acc.z += __shfl_xor(acc.z, 32, 64);
            acc.w += __shfl_xor(acc.w, 32, 64);
            // lane t holds agg-sum for features 4t..4t+3 (all groups identical)

            const float inv = 1.0f / fmaxf((float)(e1 - e0), 1.0f);
            float hacc = 0.f;
            #pragma unroll
            for (int k0 = 0; k0 < 16; ++k0) {
                const float4 wv = Wt2[k0 * 64 + lane];
                hacc = fmaf(bcastf(acc.x, k0), wv.x, hacc);
                hacc = fmaf(bcastf(acc.y, k0), wv.y, hacc);
                hacc = fmaf(bcastf(acc.z, k0), wv.z, hacc);
                hacc = fmaf(bcastf(acc.w, k0), wv.w, hacc);
            }
            hacc *= inv;                        // (agg*inv)@W == inv*(agg@W)
            const float hv = hacc > 0.f ? hacc : expm1f(hacc);
            h[(size_t)node * D + lane] = hv;
            s  += hv;
            s2 += hv * hv;
        }
    }

    red[0][threadIdx.x] = s;
    red[1][threadIdx.x] = s2;
    __syncthreads();
    if (threadIdx.x < 64) {
        float ts  = red[0][threadIdx.x] + red[0][threadIdx.x + 64] +
                    red[0][threadIdx.x + 128] + red[0][threadIdx.x + 192];
        float ts2 = red[1][threadIdx.x] + red[1][threadIdx.x + 64] +
                    red[1][threadIdx.x + 128] + red[1][threadIdx.x + 192];
        atomicAdd(&stats[threadIdx.x],      ts);
        atomicAdd(&stats[64 + threadIdx.x], ts2);
    }
}

// ---------------------------------------------------------------------------
// BatchNorm finalize, float4-vectorized streaming.
// ---------------------------------------------------------------------------
__global__ __launch_bounds__(256) void bn_kernel(
        const float4* __restrict__ h,
        const float*  __restrict__ stats,
        const float*  __restrict__ gamma,
        const float*  __restrict__ beta,
        float4* __restrict__ out) {
    int gid = blockIdx.x * 256 + threadIdx.x;     // over NN*D/4
    if (gid >= NN * D / 4) return;
    const int c0 = (gid & 15) * 4;
    const float4 v = h[gid];
    float4 r;
    const float* vv = (const float*)&v;
    float* rr = (float*)&r;
    #pragma unroll
    for (int k = 0; k < 4; ++k) {
        const int c = c0 + k;
        const float mu  = stats[c] * (1.0f / NN);
        const float var = stats[64 + c] * (1.0f / NN) - mu * mu;
        const float is  = rsqrtf(var + BN_EPS);
        rr[k] = (vv[k] - mu) * is * gamma[c] + beta[c];
    }
    out[gid] = r;
}

extern "C" void kernel_launch(void* const* d_in, const int* in_sizes, int n_in,
                              void* d_out, int out_size, void* d_ws, size_t ws_size,
                              hipStream_t stream) {
    const float* x     = (const float*)d_in[0];
    const int*   ei    = (const int*)  d_in[1];
    const float* W     = (const float*)d_in[2];
    const float* gamma = (const float*)d_in[3];
    const float* beta  = (const float*)d_in[4];
    float* out = (float*)d_out;

    // workspace layout (4B units):
    // [buf NN*D][count NNP][stats 128][exc NNP][start NN+1][cursor NN]
    // [bsum 128][boff 128][srcSorted NE]
    float* buf       = (float*)d_ws;
    int*   count     = (int*)(buf + (size_t)NN * D);
    float* stats     = (float*)(count + NNP);
    int*   exc       = (int*)(stats + 128);
    int*   start     = exc + NNP;
    int*   cursor    = start + NN + 1;
    int*   bsum      = cursor + NN;
    int*   boff      = bsum + 128;
    int*   srcSorted = boff + 128;

    // zero count (incl. padding) + stats — contiguous
    hipMemsetAsync(count, 0, (size_t)(NNP + 128) * sizeof(int), stream);

    hist_kernel   <<<(NE + 255) / 256, 256, 0, stream>>>(ei, count);
    scan1_kernel  <<<NBLK, 256, 0, stream>>>((const int4*)count, (int4*)exc, bsum);
    scan2_kernel  <<<1, 128, 0, stream>>>(bsum, boff);
    scan3_kernel  <<<(NN + 255) / 256, 256, 0, stream>>>(exc, boff, start, cursor);
    reorder_kernel<<<(NE + 255) / 256, 256, 0, stream>>>(ei, cursor, srcSorted);
    agg_gemm_kernel<<<2048, 256, 0, stream>>>(
        (const float4*)x, start, srcSorted, W, buf, stats);
    bn_kernel     <<<(NN * D / 4 + 255) / 256, 256, 0, stream>>>(
        (const float4*)buf, stats, gamma, beta, (float4*)out);
}